// Round 4
// baseline (49.990 us; speedup 1.0000x reference)
//
#include <hip/hip_runtime.h>
#include <hip/hip_bf16.h>

// Analytic reduction of the reference:
//   angles = pi*tanh(MLP(x));  <Z0> = sin(theta1)*sin(theta2)  (theta0, q_params cancel)
//   out = sigmoid(5*<Z0>)
// Memory-bound on streaming x (205 MB). Round 4: DRAM-burst grouping.
//   - K processed in groups of 4 MFMA-steps: each wave reads 512 B CONTIGUOUS
//     per row per group (vs 128 B) -> 4x longer HBM bursts, fewer page hops.
//   - A double-buffered in registers (A0/A1, parity-static), barrier-free loop.
//   - W1 staged once to LDS in B-frag order; raw barrier (lgkmcnt only) so the
//     pre-issued A loads stay in flight across it.

#define KDIM 784
#define BMB 256
#define NSTEP 25          // 6 groups of 4 + tail step 24 (k=768..783, half tile)
#define H1STR 66          // h1 LDS stride (words): 2-way banks (free)

using f32x4 = __attribute__((ext_vector_type(4))) float;
using s16x8 = __attribute__((ext_vector_type(8))) short;

union LdsU {
    uint4 bfr[NSTEP * 4 * 64];            // 102400 B: W1 frags [step][n][lane]
    struct {
        float h1[BMB * H1STR];            // 67584 B
        float part[4][BMB][2];            // 8192 B
    } t;
};

__device__ __forceinline__ ushort f2bf(float f) {
    uint b = __float_as_uint(f);
    b += 0x7FFFu + ((b >> 16) & 1u);      // RNE
    return (ushort)(b >> 16);
}
__device__ __forceinline__ uint pack2(float lo, float hi) {
    return (uint)f2bf(lo) | ((uint)f2bf(hi) << 16);
}
__device__ __forceinline__ uint4 pack8(float4 a, float4 b) {
    return make_uint4(pack2(a.x, a.y), pack2(a.z, a.w),
                      pack2(b.x, b.y), pack2(b.z, b.w));
}
__device__ __forceinline__ s16x8 asfrag(uint4 p) {
    union { uint4 u; s16x8 s; } c; c.u = p; return c.s;
}

__global__ void __launch_bounds__(1024, 4) hybrid_kernel(
    const float* __restrict__ x, const float* __restrict__ W1,
    const float* __restrict__ b1, const float* __restrict__ W2,
    const float* __restrict__ b2, const float* __restrict__ W3,
    const float* __restrict__ b3, float* __restrict__ out, int B)
{
    __shared__ LdsU lds;
    const int tid  = threadIdx.x;
    const int wave = tid >> 6, lane = tid & 63;
    const int row0 = blockIdx.x * BMB;

    // A addressing: lane owns row (wave*16 + (lane&15)), k-offset (lane>>4)*8
    const int kl = (lane >> 4) << 3;
    int arow = row0 + wave * 16 + (lane & 15);
    arow = arow < B ? arow : B - 1;                  // B % 256 == 0 in practice
    const float* abase = x + (size_t)arow * KDIM + kl;

    float4 A0[8], A1[8];                             // 2 groups x 4 steps x 8 floats

    // group g covers k in [g*128, g*128+128): 512 B contiguous per row per wave
    auto loadG = [&](int g, float4 (&Ap)[8]) {
        const float* p = abase + g * 128;
        #pragma unroll
        for (int s = 0; s < 4; ++s) {
            Ap[2 * s]     = *(const float4*)(p + s * 32);
            Ap[2 * s + 1] = *(const float4*)(p + s * 32 + 4);
        }
    };

    loadG(0, A0);                                    // in flight during prologue
    loadG(1, A1);

    // stage W1 -> LDS in B-frag order: chunk c = (step, n, lane16B)
    for (int c = tid; c < NSTEP * 4 * 64; c += 1024) {
        int s = c >> 8, n = (c >> 6) & 3, l = c & 63;
        int k0  = s * 32 + ((l >> 4) << 3);
        int col = n * 16 + (l & 15);
        float4 w0 = make_float4(0.f, 0.f, 0.f, 0.f), w1 = w0;
        if (k0 < KDIM) {                             // tail zero-fill (784%8==0)
            const float* p = W1 + (size_t)col * KDIM + k0;
            w0 = *(const float4*)p;
            w1 = *(const float4*)(p + 4);
        }
        lds.bfr[c] = pack8(w0, w1);
    }

    f32x4 acc[4];
    #pragma unroll
    for (int n = 0; n < 4; ++n)
        #pragma unroll
        for (int j = 0; j < 4; ++j) acc[n][j] = 0.f;

    // raw barrier: drain only LDS writes, keep the 16 A loads in flight
    asm volatile("s_waitcnt lgkmcnt(0)" ::: "memory");
    __builtin_amdgcn_s_barrier();
    __builtin_amdgcn_sched_barrier(0);

    #define STEP(s, u0, u1)                                                        \
        {                                                                          \
            s16x8 af = asfrag(pack8(u0, u1));                                      \
            const uint4* bp = &lds.bfr[(s) * 256 + lane];                          \
            _Pragma("unroll")                                                      \
            for (int n = 0; n < 4; ++n)                                            \
                acc[n] = __builtin_amdgcn_mfma_f32_16x16x32_bf16(                  \
                    af, asfrag(bp[n * 64]), acc[n], 0, 0, 0);                      \
        }

    auto computeG = [&](int g, float4 (&Ap)[8]) {
        #pragma unroll
        for (int s = 0; s < 4; ++s)
            STEP(g * 4 + s, Ap[2 * s], Ap[2 * s + 1]);
    };

    computeG(0, A0); loadG(2, A0);
    computeG(1, A1); loadG(3, A1);
    computeG(2, A0); loadG(4, A0);
    computeG(3, A1); loadG(5, A1);
    computeG(4, A0);
    {   // tail step 24 (k=768..783): only lanes with kl<16 carry data
        float4 z = make_float4(0.f, 0.f, 0.f, 0.f);
        float4 t0 = z, t1 = z;
        if (kl < 16) {
            t0 = *(const float4*)(abase + 768);
            t1 = *(const float4*)(abase + 772);
        }
        A0[0] = t0; A0[1] = t1;
    }
    computeG(5, A1);
    STEP(24, A0[0], A0[1]);
    #undef STEP

    __syncthreads();                                 // B-frag reads done; reuse LDS

    // h1 = relu(acc + b1); C layout (m89): col = n*16+(lane&15), row = (lane>>4)*4+j
    #pragma unroll
    for (int n = 0; n < 4; ++n) {
        int c = n * 16 + (lane & 15);
        float bias = b1[c];
        #pragma unroll
        for (int j = 0; j < 4; ++j) {
            int r = wave * 16 + (lane >> 4) * 4 + j;
            lds.t.h1[r * H1STR + c] = fmaxf(acc[n][j] + bias, 0.f);
        }
    }
    __syncthreads();

    // layers 2+3: row = tid&255, q = tid>>8
    {
        const int row = tid & 255, q = tid >> 8;
        const float* h1p = &lds.t.h1[row * H1STR];
        float4 hv[16];
        #pragma unroll
        for (int k4 = 0; k4 < 16; ++k4) hv[k4] = *(const float4*)(h1p + k4 * 4);
        float a1 = 0.f, a2 = 0.f;
        #pragma unroll
        for (int jj = 0; jj < 4; ++jj) {
            int j2 = q * 4 + jj;
            float s = b2[j2];
            #pragma unroll
            for (int k4 = 0; k4 < 16; ++k4) {
                const float4 w = *(const float4*)(W2 + j2 * 64 + k4 * 4);
                s = fmaf(hv[k4].x, w.x, s); s = fmaf(hv[k4].y, w.y, s);
                s = fmaf(hv[k4].z, w.z, s); s = fmaf(hv[k4].w, w.w, s);
            }
            s = fmaxf(s, 0.f);
            a1 = fmaf(s, W3[16 + j2], a1);
            a2 = fmaf(s, W3[32 + j2], a2);
        }
        lds.t.part[q][row][0] = a1;
        lds.t.part[q][row][1] = a2;
    }
    __syncthreads();

    if (tid < BMB) {
        int grow = row0 + tid;
        if (grow < B) {
            float a1 = b3[1] + lds.t.part[0][tid][0] + lds.t.part[1][tid][0]
                             + lds.t.part[2][tid][0] + lds.t.part[3][tid][0];
            float a2 = b3[2] + lds.t.part[0][tid][1] + lds.t.part[1][tid][1]
                             + lds.t.part[2][tid][1] + lds.t.part[3][tid][1];
            float t1 = 1.f - 2.f / (__expf(2.f * a1) + 1.f);   // tanh
            float t2 = 1.f - 2.f / (__expf(2.f * a2) + 1.f);
            const float PI = 3.14159265358979323846f;
            float z0 = __sinf(PI * t1) * __sinf(PI * t2);
            out[grow] = 1.f / (1.f + __expf(-5.f * z0));
        }
    }
}

extern "C" void kernel_launch(void* const* d_in, const int* in_sizes, int n_in,
                              void* d_out, int out_size, void* d_ws, size_t ws_size,
                              hipStream_t stream) {
    const float* x  = (const float*)d_in[0];
    const float* W1 = (const float*)d_in[1];
    const float* b1 = (const float*)d_in[2];
    const float* W2 = (const float*)d_in[3];
    const float* b2 = (const float*)d_in[4];
    const float* W3 = (const float*)d_in[5];
    const float* b3 = (const float*)d_in[6];
    // d_in[7] = q_params: unused (RZ phases cancel in |psi|^2)
    int B = in_sizes[0] / KDIM;
    int grid = (B + BMB - 1) / BMB;
    hybrid_kernel<<<grid, 1024, 0, stream>>>(x, W1, b1, W2, b2, W3, b3, (float*)d_out, B);
}

// Round 5
// 48.704 us; speedup vs baseline: 1.0264x; 1.0264x over previous
//
#include <hip/hip_runtime.h>
#include <hip/hip_bf16.h>

// Analytic reduction of the reference:
//   angles = pi*tanh(MLP(x));  <Z0> = sin(theta1)*sin(theta2)  (theta0, q_params cancel)
//   out = sigmoid(5*<Z0>)
// Memory-bound on streaming x (205 MB). Round 5: DENSE per-wave global loads.
//   Theory: all prior rounds scattered each wave-load over 16 rows (16 B/lane,
//   consecutive lanes on different rows) -> VMEM request fragmentation caps
//   reads at ~4.5 TB/s. Now 8 consecutive lanes read 128 B contiguous per row
//   (full-line merges), A goes through a double-buffered LDS chunk (bank-tiled
//   80 B row stride), one lgkm-only barrier per K-step, loads never drained.

#define KDIM 784
#define BMB 256
#define NSTEP 25          // 24 full K-chunks of 32 + half chunk 24 (k=768..783)
#define H1STR 66          // h1 LDS stride (words): 2-way banks (free)
#define AROWU2 10         // uint2 per A-row in chunk buf (80 B: 64 data + 16 pad)

using f32x4 = __attribute__((ext_vector_type(4))) float;
using s16x8 = __attribute__((ext_vector_type(8))) short;

struct Lds {
    union {
        uint4 bfr[NSTEP * 4 * 64];                        // 102400 B: W1 frags [step][n][lane]
        struct { float h1[BMB * H1STR]; float part[4][BMB][2]; } t;   // 75776 B
    } u;
    uint2 abuf[2][BMB * AROWU2];                          // 2 x 20480 B A chunk bufs
};

__device__ __forceinline__ ushort f2bf(float f) {
    uint b = __float_as_uint(f);
    b += 0x7FFFu + ((b >> 16) & 1u);      // RNE
    return (ushort)(b >> 16);
}
__device__ __forceinline__ uint pack2(float lo, float hi) {
    return (uint)f2bf(lo) | ((uint)f2bf(hi) << 16);
}
__device__ __forceinline__ uint4 pack8(float4 a, float4 b) {
    return make_uint4(pack2(a.x, a.y), pack2(a.z, a.w),
                      pack2(b.x, b.y), pack2(b.z, b.w));
}
__device__ __forceinline__ s16x8 asfrag(uint4 p) {
    union { uint4 u; s16x8 s; } c; c.u = p; return c.s;
}

__global__ void __launch_bounds__(1024, 4) hybrid_kernel(
    const float* __restrict__ x, const float* __restrict__ W1,
    const float* __restrict__ b1, const float* __restrict__ W2,
    const float* __restrict__ b2, const float* __restrict__ W3,
    const float* __restrict__ b3, float* __restrict__ out, int B)
{
    __shared__ Lds lds;
    const int tid  = threadIdx.x;
    const int wave = tid >> 6, lane = tid & 63;
    const int row0 = blockIdx.x * BMB;

    // dense A staging: thread t -> row (t>>3), k-slot (t&7)*4 (16 B each).
    // 8 consecutive lanes cover 128 B contiguous of one row -> full-line merges.
    const int r0  = tid >> 3;              // 0..127 (pass0); pass1 = +128
    const int sl4 = (tid & 7) << 2;        // k word offset 0..28
    int ra = row0 + r0;        ra = ra < B ? ra : B - 1;
    int rb = row0 + r0 + 128;  rb = rb < B ? rb : B - 1;
    const float* pa = x + (size_t)ra * KDIM + sl4;
    const float* pb = x + (size_t)rb * KDIM + sl4;

    const int w0off = r0 * AROWU2 + (tid & 7);            // uint2 index, pass0
    const int w1off = w0off + 128 * AROWU2;               // pass1
    // A-frag read: row = wave*16+(lane&15), kgroup = lane>>4 (16 B, b128-aligned)
    const int frag_off = (wave * 16 + (lane & 15)) * AROWU2 + ((lane >> 4) << 1);

    const float4 z4 = make_float4(0.f, 0.f, 0.f, 0.f);
    // parity-named prefetch sets (rule #20): SetA = even chunks, SetB = odd
    float4 A0 = *(const float4*)(pa);       float4 A1 = *(const float4*)(pb);        // chunk 0
    float4 B0 = *(const float4*)(pa + 32);  float4 B1 = *(const float4*)(pb + 32);   // chunk 1

    // stage W1 -> LDS in B-frag order (covers chunk-load latency)
    for (int c = tid; c < NSTEP * 4 * 64; c += 1024) {
        int s = c >> 8, n = (c >> 6) & 3, l = c & 63;
        int k0  = s * 32 + ((l >> 4) << 3);
        int col = n * 16 + (l & 15);
        float4 w0 = z4, w1 = z4;
        if (k0 < KDIM) {                   // tail zero-fill (784 % 8 == 0)
            const float* p = W1 + (size_t)col * KDIM + k0;
            w0 = *(const float4*)p;
            w1 = *(const float4*)(p + 4);
        }
        lds.u.bfr[c] = pack8(w0, w1);
    }

    f32x4 acc[4];
    #pragma unroll
    for (int n = 0; n < 4; ++n)
        #pragma unroll
        for (int j = 0; j < 4; ++j) acc[n][j] = 0.f;

    // pack chunk 0 -> buf0, refill SetA with chunk 2
    lds.abuf[0][w0off] = make_uint2(pack2(A0.x, A0.y), pack2(A0.z, A0.w));
    lds.abuf[0][w1off] = make_uint2(pack2(A1.x, A1.y), pack2(A1.z, A1.w));
    A0 = *(const float4*)(pa + 64);  A1 = *(const float4*)(pb + 64);

    asm volatile("s_waitcnt lgkmcnt(0)" ::: "memory");    // LDS writes done; loads stay in flight
    __builtin_amdgcn_s_barrier();
    __builtin_amdgcn_sched_barrier(0);

    // per K-step: frag-read buf[p] | pack chunk i+1 -> buf[p^1] | load chunk i+3
    //             | lgkm drain | barrier | 4 MFMA.   Loads never vmcnt(0)-drained.
    auto iterStep = [&](int i, float4& sa, float4& sb) {
        const int p = i & 1;
        s16x8 af = *(const s16x8*)&lds.abuf[p][frag_off];
        lds.abuf[p ^ 1][w0off] = make_uint2(pack2(sa.x, sa.y), pack2(sa.z, sa.w));
        lds.abuf[p ^ 1][w1off] = make_uint2(pack2(sb.x, sb.y), pack2(sb.z, sb.w));
        if (i <= 21) {                     // chunk i+3 exists (<= 24)
            const int k = (i + 3) * 32;
            if (k + sl4 < KDIM) {          // partial only for chunk 24 (slots 4-7)
                sa = *(const float4*)(pa + k);
                sb = *(const float4*)(pb + k);
            } else { sa = z4; sb = z4; }
        }
        asm volatile("s_waitcnt lgkmcnt(0)" ::: "memory");
        __builtin_amdgcn_s_barrier();
        const uint4* bp = &lds.u.bfr[i * 256 + lane];
        #pragma unroll
        for (int n = 0; n < 4; ++n)
            acc[n] = __builtin_amdgcn_mfma_f32_16x16x32_bf16(
                af, asfrag(bp[n * 64]), acc[n], 0, 0, 0);
    };

    for (int ii = 0; ii < 12; ++ii) {
        iterStep(2 * ii,     B0, B1);      // even i packs odd chunk (SetB)
        iterStep(2 * ii + 1, A0, A1);      // odd i packs even chunk (SetA)
    }
    {   // iter 24 (chunk 24 packed at iter 23 into buf0): no pack, no load
        s16x8 af = *(const s16x8*)&lds.abuf[0][frag_off];
        const uint4* bp = &lds.u.bfr[24 * 256 + lane];
        #pragma unroll
        for (int n = 0; n < 4; ++n)
            acc[n] = __builtin_amdgcn_mfma_f32_16x16x32_bf16(
                af, asfrag(bp[n * 64]), acc[n], 0, 0, 0);
    }

    __syncthreads();                       // frag reads done; reuse LDS for h1

    // h1 = relu(acc + b1); C layout (m89): col = n*16+(lane&15), row = (lane>>4)*4+j
    #pragma unroll
    for (int n = 0; n < 4; ++n) {
        int c = n * 16 + (lane & 15);
        float bias = b1[c];
        #pragma unroll
        for (int j = 0; j < 4; ++j) {
            int r = wave * 16 + (lane >> 4) * 4 + j;
            lds.u.t.h1[r * H1STR + c] = fmaxf(acc[n][j] + bias, 0.f);
        }
    }
    __syncthreads();

    // layers 2+3: row = tid&255, q = tid>>8
    {
        const int row = tid & 255, q = tid >> 8;
        const float* h1p = &lds.u.t.h1[row * H1STR];
        float4 hv[16];
        #pragma unroll
        for (int k4 = 0; k4 < 16; ++k4) hv[k4] = *(const float4*)(h1p + k4 * 4);
        float a1 = 0.f, a2 = 0.f;
        #pragma unroll
        for (int jj = 0; jj < 4; ++jj) {
            int j2 = q * 4 + jj;
            float s = b2[j2];
            #pragma unroll
            for (int k4 = 0; k4 < 16; ++k4) {
                const float4 w = *(const float4*)(W2 + j2 * 64 + k4 * 4);
                s = fmaf(hv[k4].x, w.x, s); s = fmaf(hv[k4].y, w.y, s);
                s = fmaf(hv[k4].z, w.z, s); s = fmaf(hv[k4].w, w.w, s);
            }
            s = fmaxf(s, 0.f);
            a1 = fmaf(s, W3[16 + j2], a1);
            a2 = fmaf(s, W3[32 + j2], a2);
        }
        lds.u.t.part[q][row][0] = a1;
        lds.u.t.part[q][row][1] = a2;
    }
    __syncthreads();

    if (tid < BMB) {
        int grow = row0 + tid;
        if (grow < B) {
            float a1 = b3[1] + lds.u.t.part[0][tid][0] + lds.u.t.part[1][tid][0]
                             + lds.u.t.part[2][tid][0] + lds.u.t.part[3][tid][0];
            float a2 = b3[2] + lds.u.t.part[0][tid][1] + lds.u.t.part[1][tid][1]
                             + lds.u.t.part[2][tid][1] + lds.u.t.part[3][tid][1];
            float t1 = 1.f - 2.f / (__expf(2.f * a1) + 1.f);   // tanh
            float t2 = 1.f - 2.f / (__expf(2.f * a2) + 1.f);
            const float PI = 3.14159265358979323846f;
            float z0 = __sinf(PI * t1) * __sinf(PI * t2);
            out[grow] = 1.f / (1.f + __expf(-5.f * z0));
        }
    }
}

extern "C" void kernel_launch(void* const* d_in, const int* in_sizes, int n_in,
                              void* d_out, int out_size, void* d_ws, size_t ws_size,
                              hipStream_t stream) {
    const float* x  = (const float*)d_in[0];
    const float* W1 = (const float*)d_in[1];
    const float* b1 = (const float*)d_in[2];
    const float* W2 = (const float*)d_in[3];
    const float* b2 = (const float*)d_in[4];
    const float* W3 = (const float*)d_in[5];
    const float* b3 = (const float*)d_in[6];
    // d_in[7] = q_params: unused (RZ phases cancel in |psi|^2)
    int B = in_sizes[0] / KDIM;
    int grid = (B + BMB - 1) / BMB;
    hybrid_kernel<<<grid, 1024, 0, stream>>>(x, W1, b1, W2, b2, W3, b3, (float*)d_out, B);
}